// Round 8
// baseline (345.777 us; speedup 1.0000x reference)
//
#include <hip/hip_runtime.h>
#include <math.h>

// VGAE Encoder on MI355X — R8.
// R7 found: 3.2MB quarter tables thrash vs ~8.6MB/XCD stream working set
// (FETCH 176MB ~ 6x table re-fetch). R8: eighth-split — each XCD owns a
// 1.6MB 4-channel table slice read by it alone; sorted_src re-streamed 8x
// (cheap). rows packed as {beg|deg<<21, di} in 8B. Plain loads (nt reverted).

#define CAPB  1280     // per-bucket total edge capacity (mean 1024, +8 sigma)
#define SCAP  224      // per-slice capacity (mean 128, +8.5 sigma)
#define NSL   8        // binfill slices (XCDs)

typedef float f32x4 __attribute__((ext_vector_type(4)));

// ---------- pass A: bin edges into (slice, bucket) sub-regions ----------
__global__ void k_binfill(const int* __restrict__ src, const int* __restrict__ dst,
                          int* __restrict__ bcur, unsigned* __restrict__ pairs,
                          int E, int nbucket) {
    int sl = blockIdx.x & (NSL - 1);               // heuristic XCD id
    int* cur = bcur + sl * nbucket;
    unsigned* pp = pairs + (size_t)sl * nbucket * SCAP;
    int i = blockIdx.x * blockDim.x + threadIdx.x;
    int stride = gridDim.x * blockDim.x;
    for (; i < E; i += stride) {
        int d = __builtin_nontemporal_load(&dst[i]);
        unsigned s = (unsigned)__builtin_nontemporal_load(&src[i]);
        int b = d >> 6;
        int p = atomicAdd(&cur[b], 1);
        pp[b * SCAP + p] = ((unsigned)(d & 63) << 20) | s;   // src < 2^20
    }
}

// ---------- pass B: wave-per-bucket counting sort over 8 slices ----------
__global__ void k_bucket(const unsigned* __restrict__ pairs, const int* __restrict__ bcur,
                         uint2* __restrict__ rows2, float* __restrict__ dis,
                         int* __restrict__ sorted_src, int nbucket, int N) {
    __shared__ int hist[4][64];
    __shared__ int lbuf[4][CAPB];
    int w = threadIdx.x >> 6, lane = threadIdx.x & 63;
    int b = blockIdx.x * 4 + w;
    if (b >= nbucket) return;
    int ebase = b * CAPB;

    hist[w][lane] = 0;
    for (int sl = 0; sl < NSL; ++sl) {
        int size = bcur[sl * nbucket + b];
        const unsigned* pp = pairs + ((size_t)sl * nbucket + b) * SCAP;
        for (int e = lane; e < size; e += 64)
            atomicAdd(&hist[w][pp[e] >> 20], 1);
    }
    int v = hist[w][lane];
    int incl = v;
    for (int off = 1; off < 64; off <<= 1) {
        int a = __shfl_up(incl, off, 64);
        if (lane >= off) incl += a;
    }
    int excl = incl - v;
    int n = (b << 6) + lane;
    if (n < N) {
        float di = rsqrtf(1.0f + (float)v);
        rows2[n] = make_uint2((unsigned)(ebase + excl) | ((unsigned)v << 21),
                              __float_as_uint(di));
        dis[n] = di;
    }
    hist[w][lane] = excl;                       // local cursor
    int tot = __shfl(incl, 63, 64);             // bucket total
    for (int sl = 0; sl < NSL; ++sl) {
        int size = bcur[sl * nbucket + b];
        const unsigned* pp = pairs + ((size_t)sl * nbucket + b) * SCAP;
        for (int e = lane; e < size; e += 64) {
            unsigned pr = pp[e];
            int slot = atomicAdd(&hist[w][pr >> 20], 1);
            lbuf[w][slot] = (int)(pr & 0xFFFFFu);
        }
    }
    for (int e = lane; e < tot; e += 64)        // coalesced drain
        sorted_src[ebase + e] = lbuf[w][e];
}

// ---------- fused gather + dense MLP: 32 lanes per node ----------
// ax = A_norm x; h = relu(ax W1 + b1); hml' = dis[n] * (h [W_mu|W_logstd])
// stored as 8 eighth tables hml8[oct][N][4] (1.6MB each).
__global__ void k_mlp(const float* __restrict__ x, const uint2* __restrict__ rows2,
                      const int* __restrict__ sorted_src, const float* __restrict__ dis,
                      const float* __restrict__ W1, const float* __restrict__ b1,
                      const float* __restrict__ W_mu, const float* __restrict__ W_logstd,
                      float* __restrict__ hml8, int N) {
    __shared__ float W1s[128];
    __shared__ float b1s[64];
    __shared__ float Wcs[64 * 32];
    for (int t = threadIdx.x; t < 128; t += 256) W1s[t] = W1[t];
    for (int t = threadIdx.x; t < 64; t += 256) b1s[t] = b1[t];
    for (int t = threadIdx.x; t < 2048; t += 256) {
        int k = t >> 5, c = t & 31;
        Wcs[t] = (c < 16) ? W_mu[k * 16 + c] : W_logstd[k * 16 + (c - 16)];
    }
    __syncthreads();
    int node = blockIdx.x * 8 + (threadIdx.x >> 5);
    int c = threadIdx.x & 31;
    if (node >= N) return;
    const float2* x2 = (const float2*)x;
    uint2 r = rows2[node];
    int beg = (int)(r.x & 0x1FFFFFu);
    int end = beg + (int)(r.x >> 21);
    float di = __uint_as_float(r.y);
    float axx = 0.0f, axy = 0.0f;
    for (int e = beg + c; e < end; e += 32) {
        int s = sorted_src[e];
        float w = di * dis[s];
        float2 u = x2[s];
        axx = fmaf(w, u.x, axx);
        axy = fmaf(w, u.y, axy);
    }
#pragma unroll
    for (int off = 16; off; off >>= 1) {
        axx += __shfl_xor(axx, off, 32);
        axy += __shfl_xor(axy, off, 32);
    }
    float2 xv = x2[node];
    axx = fmaf(di * di, xv.x, axx);
    axy = fmaf(di * di, xv.y, axy);
    float h0 = fmaxf(fmaf(axx, W1s[c],      fmaf(axy, W1s[64 + c],  b1s[c])),      0.0f);
    float h1 = fmaxf(fmaf(axx, W1s[32 + c], fmaf(axy, W1s[96 + c],  b1s[32 + c])), 0.0f);
    float acc = 0.0f;
#pragma unroll
    for (int k = 0; k < 32; ++k) {
        float hk = __shfl(h0, k, 32);
        acc = fmaf(hk, Wcs[k * 32 + c], acc);
    }
#pragma unroll
    for (int k = 0; k < 32; ++k) {
        float hk = __shfl(h1, k, 32);
        acc = fmaf(hk, Wcs[(k + 32) * 32 + c], acc);
    }
    // hml' = dis * hml, eighth table (c>>2), channel (c&3)
    hml8[(size_t)(c >> 2) * N * 4 + (size_t)node * 4 + (c & 3)] = di * acc;
}

// ---------- layer-2 aggregation: 8 eighths, 1 XCD each, one launch ----------
// out[n] = di * (hml'[n] + sum_s hml'[s]) + bias ; thread-per-node, float4.
__global__ void k_agg2(const float* __restrict__ hml8, const uint2* __restrict__ rows2,
                       const int* __restrict__ sorted_src,
                       const float* __restrict__ b_mu, const float* __restrict__ b_logstd,
                       float* __restrict__ out, int N) {
    int oct = blockIdx.x & 7;                       // 1 eighth : 1 XCD
    int node = (blockIdx.x >> 3) * 256 + threadIdx.x;
    if (node >= N) return;
    const float4* h4 = (const float4*)(hml8 + (size_t)oct * N * 4);
    uint2 r = rows2[node];
    int beg = (int)(r.x & 0x1FFFFFu);
    int end = beg + (int)(r.x >> 21);
    float di = __uint_as_float(r.y);
    float4 acc = h4[node];                          // self-loop hml'[n]
    for (int k = beg; k < end; ++k) {
        int s = sorted_src[k];
        float4 u = h4[s];
        acc.x += u.x; acc.y += u.y; acc.z += u.z; acc.w += u.w;
    }
    const float* bp = (oct < 4 ? b_mu + 4 * oct : b_logstd + 4 * (oct - 4));
    f32x4 res = { fmaf(di, acc.x, bp[0]), fmaf(di, acc.y, bp[1]),
                  fmaf(di, acc.z, bp[2]), fmaf(di, acc.w, bp[3]) };
    float* op = out + ((oct < 4 ? (size_t)0 : (size_t)N) + node) * 16 + ((oct & 3) << 2);
    *(f32x4*)op = res;
}

extern "C" void kernel_launch(void* const* d_in, const int* in_sizes, int n_in,
                              void* d_out, int out_size, void* d_ws, size_t ws_size,
                              hipStream_t stream) {
    const float* x        = (const float*)d_in[0];
    const int*   eidx     = (const int*)d_in[1];
    const float* W1       = (const float*)d_in[2];
    const float* b1       = (const float*)d_in[3];
    const float* W_mu     = (const float*)d_in[4];
    const float* b_mu     = (const float*)d_in[5];
    const float* W_logstd = (const float*)d_in[6];
    const float* b_logstd = (const float*)d_in[7];
    float* out = (float*)d_out;

    const int N = in_sizes[0] / 2;            // 100000
    const int E = in_sizes[1] / 2;            // 1600000
    const int NBUCKET = (N + 63) >> 6;        // 1563

    const int* src = eidx;
    const int* dst = eidx + E;

    char* w = (char*)d_ws;
    auto alloc = [&](size_t bytes) -> void* {
        void* p = (void*)w;
        w += (bytes + 255) & ~(size_t)255;
        return p;
    };
    int*      bcur       = (int*)     alloc((size_t)NSL * NBUCKET * 4);
    unsigned* pairs      = (unsigned*)alloc((size_t)NSL * NBUCKET * SCAP * 4);
    int*      sorted_src = (int*)     alloc((size_t)NBUCKET * CAPB * 4);
    uint2*    rows2      = (uint2*)   alloc((size_t)N * 8);
    float*    dis        = (float*)   alloc((size_t)N * 4);
    float*    hml8       = (float*)   alloc((size_t)N * 32 * 4);

    hipMemsetAsync(bcur, 0, (size_t)NSL * NBUCKET * 4, stream);

    k_binfill<<<2048, 256, 0, stream>>>(src, dst, bcur, pairs, E, NBUCKET);
    k_bucket <<<(NBUCKET + 3) / 4, 256, 0, stream>>>(pairs, bcur, rows2, dis,
                                                     sorted_src, NBUCKET, N);
    k_mlp    <<<(N + 7) / 8, 256, 0, stream>>>(x, rows2, sorted_src, dis,
                                               W1, b1, W_mu, W_logstd, hml8, N);
    int nblk = (N + 255) / 256;               // 391 per eighth
    k_agg2   <<<nblk * 8, 256, 0, stream>>>(hml8, rows2, sorted_src,
                                            b_mu, b_logstd, out, N);
}

// Round 9
// 252.431 us; speedup vs baseline: 1.3698x; 1.3698x over previous
//
#include <hip/hip_runtime.h>
#include <hip/hip_fp16.h>
#include <math.h>

// VGAE Encoder on MI355X — R9.
// R6-R8 lesson: agg2 is bound by L2-miss fabric traffic ~= edges x 64B-line x
// passes; XCD-pinning of table slices does not work under this harness.
// R9: hml' stored as f16 -> one node row = 32ch x 2B = exactly one 64B line.
// Single-pass agg2, 4 lanes/node, 16B gather per lane per edge, f32 accum.
// Worst-case gather traffic 102MB (was 272MB measured).

#define CAPB  1280     // per-bucket total edge capacity (mean 1024, +8 sigma)
#define SCAP  224      // per-slice capacity (mean 128, +8.5 sigma)
#define NSL   8        // binfill slices

typedef float f32x4 __attribute__((ext_vector_type(4)));

__device__ __forceinline__ float2 cvt2(unsigned u) {
    __half2 h = *reinterpret_cast<__half2*>(&u);
    return __half22float2(h);
}

// ---------- pass A: bin edges into (slice, bucket) sub-regions ----------
__global__ void k_binfill(const int* __restrict__ src, const int* __restrict__ dst,
                          int* __restrict__ bcur, unsigned* __restrict__ pairs,
                          int E, int nbucket) {
    int sl = blockIdx.x & (NSL - 1);
    int* cur = bcur + sl * nbucket;
    unsigned* pp = pairs + (size_t)sl * nbucket * SCAP;
    int i = blockIdx.x * blockDim.x + threadIdx.x;
    int stride = gridDim.x * blockDim.x;
    for (; i < E; i += stride) {
        int d = __builtin_nontemporal_load(&dst[i]);
        unsigned s = (unsigned)__builtin_nontemporal_load(&src[i]);
        int b = d >> 6;
        int p = atomicAdd(&cur[b], 1);
        pp[b * SCAP + p] = ((unsigned)(d & 63) << 20) | s;   // src < 2^20
    }
}

// ---------- pass B: wave-per-bucket counting sort over 8 slices ----------
__global__ void k_bucket(const unsigned* __restrict__ pairs, const int* __restrict__ bcur,
                         uint2* __restrict__ rows2, float* __restrict__ dis,
                         int* __restrict__ sorted_src, int nbucket, int N) {
    __shared__ int hist[4][64];
    __shared__ int lbuf[4][CAPB];
    int w = threadIdx.x >> 6, lane = threadIdx.x & 63;
    int b = blockIdx.x * 4 + w;
    if (b >= nbucket) return;
    int ebase = b * CAPB;

    hist[w][lane] = 0;
    for (int sl = 0; sl < NSL; ++sl) {
        int size = bcur[sl * nbucket + b];
        const unsigned* pp = pairs + ((size_t)sl * nbucket + b) * SCAP;
        for (int e = lane; e < size; e += 64)
            atomicAdd(&hist[w][pp[e] >> 20], 1);
    }
    int v = hist[w][lane];
    int incl = v;
    for (int off = 1; off < 64; off <<= 1) {
        int a = __shfl_up(incl, off, 64);
        if (lane >= off) incl += a;
    }
    int excl = incl - v;
    int n = (b << 6) + lane;
    if (n < N) {
        float di = rsqrtf(1.0f + (float)v);
        rows2[n] = make_uint2((unsigned)(ebase + excl) | ((unsigned)v << 21),
                              __float_as_uint(di));
        dis[n] = di;
    }
    hist[w][lane] = excl;                       // local cursor
    int tot = __shfl(incl, 63, 64);             // bucket total
    for (int sl = 0; sl < NSL; ++sl) {
        int size = bcur[sl * nbucket + b];
        const unsigned* pp = pairs + ((size_t)sl * nbucket + b) * SCAP;
        for (int e = lane; e < size; e += 64) {
            unsigned pr = pp[e];
            int slot = atomicAdd(&hist[w][pr >> 20], 1);
            lbuf[w][slot] = (int)(pr & 0xFFFFFu);
        }
    }
    for (int e = lane; e < tot; e += 64)        // coalesced drain
        sorted_src[ebase + e] = lbuf[w][e];
}

// ---------- fused gather + dense MLP: 32 lanes per node ----------
// ax = A_norm x; h = relu(ax W1 + b1); hml' = f16( dis[n] * (h [W_mu|W_logstd]) )
// row layout: hml16[n*32 + c], c<16 mu, c>=16 logstd — one 64B line per node.
__global__ void k_mlp(const float* __restrict__ x, const uint2* __restrict__ rows2,
                      const int* __restrict__ sorted_src, const float* __restrict__ dis,
                      const float* __restrict__ W1, const float* __restrict__ b1,
                      const float* __restrict__ W_mu, const float* __restrict__ W_logstd,
                      __half* __restrict__ hml16, int N) {
    __shared__ float W1s[128];
    __shared__ float b1s[64];
    __shared__ float Wcs[64 * 32];
    for (int t = threadIdx.x; t < 128; t += 256) W1s[t] = W1[t];
    for (int t = threadIdx.x; t < 64; t += 256) b1s[t] = b1[t];
    for (int t = threadIdx.x; t < 2048; t += 256) {
        int k = t >> 5, c = t & 31;
        Wcs[t] = (c < 16) ? W_mu[k * 16 + c] : W_logstd[k * 16 + (c - 16)];
    }
    __syncthreads();
    int node = blockIdx.x * 8 + (threadIdx.x >> 5);
    int c = threadIdx.x & 31;
    if (node >= N) return;
    const float2* x2 = (const float2*)x;
    uint2 r = rows2[node];
    int beg = (int)(r.x & 0x1FFFFFu);
    int end = beg + (int)(r.x >> 21);
    float di = __uint_as_float(r.y);
    float axx = 0.0f, axy = 0.0f;
    for (int e = beg + c; e < end; e += 32) {
        int s = sorted_src[e];
        float w = di * dis[s];
        float2 u = x2[s];
        axx = fmaf(w, u.x, axx);
        axy = fmaf(w, u.y, axy);
    }
#pragma unroll
    for (int off = 16; off; off >>= 1) {
        axx += __shfl_xor(axx, off, 32);
        axy += __shfl_xor(axy, off, 32);
    }
    float2 xv = x2[node];
    axx = fmaf(di * di, xv.x, axx);
    axy = fmaf(di * di, xv.y, axy);
    float h0 = fmaxf(fmaf(axx, W1s[c],      fmaf(axy, W1s[64 + c],  b1s[c])),      0.0f);
    float h1 = fmaxf(fmaf(axx, W1s[32 + c], fmaf(axy, W1s[96 + c],  b1s[32 + c])), 0.0f);
    float acc = 0.0f;
#pragma unroll
    for (int k = 0; k < 32; ++k) {
        float hk = __shfl(h0, k, 32);
        acc = fmaf(hk, Wcs[k * 32 + c], acc);
    }
#pragma unroll
    for (int k = 0; k < 32; ++k) {
        float hk = __shfl(h1, k, 32);
        acc = fmaf(hk, Wcs[(k + 32) * 32 + c], acc);
    }
    hml16[(size_t)node * 32 + c] = __float2half(di * acc);   // hml' = dis * hml
}

// ---------- layer-2 aggregation: single pass, 4 lanes/node, f16 table ----------
// out[n] = di * (hml'[n] + sum_s hml'[s]) + bias
__global__ void k_agg2(const __half* __restrict__ hml16, const uint2* __restrict__ rows2,
                       const int* __restrict__ sorted_src,
                       const float* __restrict__ b_mu, const float* __restrict__ b_logstd,
                       float* __restrict__ out, int N) {
    int t = blockIdx.x * blockDim.x + threadIdx.x;
    int node = t >> 2, q = t & 3;                   // lane q: channels 8q..8q+7
    if (node >= N) return;
    const uint4* h4 = (const uint4*)hml16;          // 16B = 8 f16 channels
    uint2 r = rows2[node];
    int beg = (int)(r.x & 0x1FFFFFu);
    int end = beg + (int)(r.x >> 21);
    float di = __uint_as_float(r.y);
    uint4 v = h4[(size_t)node * 4 + q];             // self-loop row
    float2 a0 = cvt2(v.x), a1 = cvt2(v.y), a2 = cvt2(v.z), a3 = cvt2(v.w);
    for (int k = beg; k < end; ++k) {
        int s = sorted_src[k];
        uint4 u = h4[(size_t)s * 4 + q];
        float2 t0 = cvt2(u.x), t1 = cvt2(u.y), t2 = cvt2(u.z), t3 = cvt2(u.w);
        a0.x += t0.x; a0.y += t0.y; a1.x += t1.x; a1.y += t1.y;
        a2.x += t2.x; a2.y += t2.y; a3.x += t3.x; a3.y += t3.y;
    }
    const float* bp = (q < 2) ? (b_mu + 8 * q) : (b_logstd + 8 * (q - 2));
    float* op = out + ((q < 2) ? (size_t)0 : (size_t)N * 16)
                    + (size_t)node * 16 + (size_t)(q & 1) * 8;
    f32x4 r0 = { fmaf(di, a0.x, bp[0]), fmaf(di, a0.y, bp[1]),
                 fmaf(di, a1.x, bp[2]), fmaf(di, a1.y, bp[3]) };
    f32x4 r1 = { fmaf(di, a2.x, bp[4]), fmaf(di, a2.y, bp[5]),
                 fmaf(di, a3.x, bp[6]), fmaf(di, a3.y, bp[7]) };
    *(f32x4*)op = r0;
    *(f32x4*)(op + 4) = r1;
}

extern "C" void kernel_launch(void* const* d_in, const int* in_sizes, int n_in,
                              void* d_out, int out_size, void* d_ws, size_t ws_size,
                              hipStream_t stream) {
    const float* x        = (const float*)d_in[0];
    const int*   eidx     = (const int*)d_in[1];
    const float* W1       = (const float*)d_in[2];
    const float* b1       = (const float*)d_in[3];
    const float* W_mu     = (const float*)d_in[4];
    const float* b_mu     = (const float*)d_in[5];
    const float* W_logstd = (const float*)d_in[6];
    const float* b_logstd = (const float*)d_in[7];
    float* out = (float*)d_out;

    const int N = in_sizes[0] / 2;            // 100000
    const int E = in_sizes[1] / 2;            // 1600000
    const int NBUCKET = (N + 63) >> 6;        // 1563

    const int* src = eidx;
    const int* dst = eidx + E;

    char* w = (char*)d_ws;
    auto alloc = [&](size_t bytes) -> void* {
        void* p = (void*)w;
        w += (bytes + 255) & ~(size_t)255;
        return p;
    };
    int*      bcur       = (int*)     alloc((size_t)NSL * NBUCKET * 4);
    unsigned* pairs      = (unsigned*)alloc((size_t)NSL * NBUCKET * SCAP * 4);
    int*      sorted_src = (int*)     alloc((size_t)NBUCKET * CAPB * 4);
    uint2*    rows2      = (uint2*)   alloc((size_t)N * 8);
    float*    dis        = (float*)   alloc((size_t)N * 4);
    __half*   hml16      = (__half*)  alloc((size_t)N * 32 * 2);

    hipMemsetAsync(bcur, 0, (size_t)NSL * NBUCKET * 4, stream);

    k_binfill<<<2048, 256, 0, stream>>>(src, dst, bcur, pairs, E, NBUCKET);
    k_bucket <<<(NBUCKET + 3) / 4, 256, 0, stream>>>(pairs, bcur, rows2, dis,
                                                     sorted_src, NBUCKET, N);
    k_mlp    <<<(N + 7) / 8, 256, 0, stream>>>(x, rows2, sorted_src, dis,
                                               W1, b1, W_mu, W_logstd, hml16, N);
    k_agg2   <<<(4 * N + 255) / 256, 256, 0, stream>>>(hml16, rows2, sorted_src,
                                                       b_mu, b_logstd, out, N);
}

// Round 10
// 250.662 us; speedup vs baseline: 1.3795x; 1.0071x over previous
//
#include <hip/hip_runtime.h>
#include <hip/hip_fp16.h>
#include <math.h>

// VGAE Encoder on MI355X — R10.
// R9: f16 table killed agg2's traffic (total 346->252us). Remaining hotspot:
// k_binfill 74us, WRITE 51MB vs 6.4MB payload — blockIdx%8 is NOT a reliable
// XCD key, lines stay partial across multiple per-XCD L2s. R10: slice by the
// REAL XCD id via s_getreg(HW_REG_XCC_ID); capacity-retry makes correctness
// independent of the id's behavior. Also fold dis into x (xd = dis*x) so
// k_mlp's per-edge gather is one 8B load + 2 adds.

#define CAPB  1280     // per-bucket total edge capacity (mean 1024, +8 sigma)
#define SCAP  256      // per-(xcd,bucket) capacity (mean 128, +12 sigma; retry spills)
#define NSL   8        // slices = XCDs

typedef float f32x4 __attribute__((ext_vector_type(4)));

__device__ __forceinline__ float2 cvt2(unsigned u) {
    __half2 h = *reinterpret_cast<__half2*>(&u);
    return __half22float2(h);
}

// ---------- pass A: bin edges into (xcd, bucket) sub-regions ----------
__global__ void k_binfill(const int* __restrict__ src, const int* __restrict__ dst,
                          int* __restrict__ bcur, unsigned* __restrict__ pairs,
                          int E, int nbucket) {
    unsigned xcd;
    asm("s_getreg_b32 %0, hwreg(HW_REG_XCC_ID)" : "=s"(xcd));
    int sl = (int)(xcd & (NSL - 1));
    int i = blockIdx.x * blockDim.x + threadIdx.x;
    int stride = gridDim.x * blockDim.x;
    for (; i < E; i += stride) {
        int d = __builtin_nontemporal_load(&dst[i]);
        unsigned s = (unsigned)__builtin_nontemporal_load(&src[i]);
        int b = d >> 6;
        unsigned pk = ((unsigned)(d & 63) << 20) | s;   // src < 2^20
        int t = sl;
        for (;;) {                                      // capacity-retry spill
            int p = atomicAdd(&bcur[t * nbucket + b], 1);
            if (p < SCAP) {
                pairs[((size_t)t * nbucket + b) * SCAP + p] = pk;
                break;
            }
            t = (t + 1) & (NSL - 1);
        }
    }
}

// ---------- pass B: wave-per-bucket counting sort over 8 slices ----------
// also emits rows2 = {beg|deg<<21, di} and xd = dis*x (folded weight).
__global__ void k_bucket(const unsigned* __restrict__ pairs, const int* __restrict__ bcur,
                         const float* __restrict__ x,
                         uint2* __restrict__ rows2, float2* __restrict__ xd,
                         int* __restrict__ sorted_src, int nbucket, int N) {
    __shared__ int hist[4][64];
    __shared__ int lbuf[4][CAPB];
    int w = threadIdx.x >> 6, lane = threadIdx.x & 63;
    int b = blockIdx.x * 4 + w;
    if (b >= nbucket) return;
    int ebase = b * CAPB;

    hist[w][lane] = 0;
    for (int sl = 0; sl < NSL; ++sl) {
        int size = min(bcur[sl * nbucket + b], SCAP);
        const unsigned* pp = pairs + ((size_t)sl * nbucket + b) * SCAP;
        for (int e = lane; e < size; e += 64)
            atomicAdd(&hist[w][pp[e] >> 20], 1);
    }
    int v = hist[w][lane];
    int incl = v;
    for (int off = 1; off < 64; off <<= 1) {
        int a = __shfl_up(incl, off, 64);
        if (lane >= off) incl += a;
    }
    int excl = incl - v;
    int n = (b << 6) + lane;
    if (n < N) {
        float di = rsqrtf(1.0f + (float)v);
        rows2[n] = make_uint2((unsigned)(ebase + excl) | ((unsigned)v << 21),
                              __float_as_uint(di));
        float2 xv = ((const float2*)x)[n];
        xd[n] = make_float2(di * xv.x, di * xv.y);
    }
    hist[w][lane] = excl;                       // local cursor
    int tot = __shfl(incl, 63, 64);             // bucket total
    for (int sl = 0; sl < NSL; ++sl) {
        int size = min(bcur[sl * nbucket + b], SCAP);
        const unsigned* pp = pairs + ((size_t)sl * nbucket + b) * SCAP;
        for (int e = lane; e < size; e += 64) {
            unsigned pr = pp[e];
            int slot = atomicAdd(&hist[w][pr >> 20], 1);
            lbuf[w][slot] = (int)(pr & 0xFFFFFu);
        }
    }
    for (int e = lane; e < tot; e += 64)        // coalesced drain
        sorted_src[ebase + e] = lbuf[w][e];
}

// ---------- fused gather + dense MLP: 32 lanes per node ----------
// ax = di*(xd[n] + sum_s xd[s]); h = relu(ax W1 + b1);
// hml' = f16( di * (h [W_mu|W_logstd]) ) — one 64B line per node.
__global__ void k_mlp(const float2* __restrict__ xd, const uint2* __restrict__ rows2,
                      const int* __restrict__ sorted_src,
                      const float* __restrict__ W1, const float* __restrict__ b1,
                      const float* __restrict__ W_mu, const float* __restrict__ W_logstd,
                      __half* __restrict__ hml16, int N) {
    __shared__ float W1s[128];
    __shared__ float b1s[64];
    __shared__ float Wcs[64 * 32];
    for (int t = threadIdx.x; t < 128; t += 256) W1s[t] = W1[t];
    for (int t = threadIdx.x; t < 64; t += 256) b1s[t] = b1[t];
    for (int t = threadIdx.x; t < 2048; t += 256) {
        int k = t >> 5, c = t & 31;
        Wcs[t] = (c < 16) ? W_mu[k * 16 + c] : W_logstd[k * 16 + (c - 16)];
    }
    __syncthreads();
    int node = blockIdx.x * 8 + (threadIdx.x >> 5);
    int c = threadIdx.x & 31;
    if (node >= N) return;
    uint2 r = rows2[node];
    int beg = (int)(r.x & 0x1FFFFFu);
    int end = beg + (int)(r.x >> 21);
    float di = __uint_as_float(r.y);
    float sx = 0.0f, sy = 0.0f;
    for (int e = beg + c; e < end; e += 32) {
        int s = sorted_src[e];
        float2 u = xd[s];
        sx += u.x;
        sy += u.y;
    }
#pragma unroll
    for (int off = 16; off; off >>= 1) {
        sx += __shfl_xor(sx, off, 32);
        sy += __shfl_xor(sy, off, 32);
    }
    float2 xn = xd[node];
    float axx = di * (sx + xn.x);
    float axy = di * (sy + xn.y);
    float h0 = fmaxf(fmaf(axx, W1s[c],      fmaf(axy, W1s[64 + c],  b1s[c])),      0.0f);
    float h1 = fmaxf(fmaf(axx, W1s[32 + c], fmaf(axy, W1s[96 + c],  b1s[32 + c])), 0.0f);
    float acc = 0.0f;
#pragma unroll
    for (int k = 0; k < 32; ++k) {
        float hk = __shfl(h0, k, 32);
        acc = fmaf(hk, Wcs[k * 32 + c], acc);
    }
#pragma unroll
    for (int k = 0; k < 32; ++k) {
        float hk = __shfl(h1, k, 32);
        acc = fmaf(hk, Wcs[(k + 32) * 32 + c], acc);
    }
    hml16[(size_t)node * 32 + c] = __float2half(di * acc);   // hml' = dis * hml
}

// ---------- layer-2 aggregation: single pass, 4 lanes/node, f16 table ----------
// out[n] = di * (hml'[n] + sum_s hml'[s]) + bias
__global__ void k_agg2(const __half* __restrict__ hml16, const uint2* __restrict__ rows2,
                       const int* __restrict__ sorted_src,
                       const float* __restrict__ b_mu, const float* __restrict__ b_logstd,
                       float* __restrict__ out, int N) {
    int t = blockIdx.x * blockDim.x + threadIdx.x;
    int node = t >> 2, q = t & 3;                   // lane q: channels 8q..8q+7
    if (node >= N) return;
    const uint4* h4 = (const uint4*)hml16;          // 16B = 8 f16 channels
    uint2 r = rows2[node];
    int beg = (int)(r.x & 0x1FFFFFu);
    int end = beg + (int)(r.x >> 21);
    float di = __uint_as_float(r.y);
    uint4 v = h4[(size_t)node * 4 + q];             // self-loop row
    float2 a0 = cvt2(v.x), a1 = cvt2(v.y), a2 = cvt2(v.z), a3 = cvt2(v.w);
    for (int k = beg; k < end; ++k) {
        int s = sorted_src[k];
        uint4 u = h4[(size_t)s * 4 + q];
        float2 t0 = cvt2(u.x), t1 = cvt2(u.y), t2 = cvt2(u.z), t3 = cvt2(u.w);
        a0.x += t0.x; a0.y += t0.y; a1.x += t1.x; a1.y += t1.y;
        a2.x += t2.x; a2.y += t2.y; a3.x += t3.x; a3.y += t3.y;
    }
    const float* bp = (q < 2) ? (b_mu + 8 * q) : (b_logstd + 8 * (q - 2));
    float* op = out + ((q < 2) ? (size_t)0 : (size_t)N * 16)
                    + (size_t)node * 16 + (size_t)(q & 1) * 8;
    f32x4 r0 = { fmaf(di, a0.x, bp[0]), fmaf(di, a0.y, bp[1]),
                 fmaf(di, a1.x, bp[2]), fmaf(di, a1.y, bp[3]) };
    f32x4 r1 = { fmaf(di, a2.x, bp[4]), fmaf(di, a2.y, bp[5]),
                 fmaf(di, a3.x, bp[6]), fmaf(di, a3.y, bp[7]) };
    *(f32x4*)op = r0;
    *(f32x4*)(op + 4) = r1;
}

extern "C" void kernel_launch(void* const* d_in, const int* in_sizes, int n_in,
                              void* d_out, int out_size, void* d_ws, size_t ws_size,
                              hipStream_t stream) {
    const float* x        = (const float*)d_in[0];
    const int*   eidx     = (const int*)d_in[1];
    const float* W1       = (const float*)d_in[2];
    const float* b1       = (const float*)d_in[3];
    const float* W_mu     = (const float*)d_in[4];
    const float* b_mu     = (const float*)d_in[5];
    const float* W_logstd = (const float*)d_in[6];
    const float* b_logstd = (const float*)d_in[7];
    float* out = (float*)d_out;

    const int N = in_sizes[0] / 2;            // 100000
    const int E = in_sizes[1] / 2;            // 1600000
    const int NBUCKET = (N + 63) >> 6;        // 1563

    const int* src = eidx;
    const int* dst = eidx + E;

    char* w = (char*)d_ws;
    auto alloc = [&](size_t bytes) -> void* {
        void* p = (void*)w;
        w += (bytes + 255) & ~(size_t)255;
        return p;
    };
    int*      bcur       = (int*)     alloc((size_t)NSL * NBUCKET * 4);
    unsigned* pairs      = (unsigned*)alloc((size_t)NSL * NBUCKET * SCAP * 4);
    int*      sorted_src = (int*)     alloc((size_t)NBUCKET * CAPB * 4);
    uint2*    rows2      = (uint2*)   alloc((size_t)N * 8);
    float2*   xd         = (float2*)  alloc((size_t)N * 8);
    __half*   hml16      = (__half*)  alloc((size_t)N * 32 * 2);

    hipMemsetAsync(bcur, 0, (size_t)NSL * NBUCKET * 4, stream);

    k_binfill<<<2048, 256, 0, stream>>>(src, dst, bcur, pairs, E, NBUCKET);
    k_bucket <<<(NBUCKET + 3) / 4, 256, 0, stream>>>(pairs, bcur, x, rows2, xd,
                                                     sorted_src, NBUCKET, N);
    k_mlp    <<<(N + 7) / 8, 256, 0, stream>>>(xd, rows2, sorted_src,
                                               W1, b1, W_mu, W_logstd, hml16, N);
    k_agg2   <<<(4 * N + 255) / 256, 256, 0, stream>>>(hml16, rows2, sorted_src,
                                                       b_mu, b_logstd, out, N);
}

// Round 11
// 190.447 us; speedup vs baseline: 1.8156x; 1.3162x over previous
//
#include <hip/hip_runtime.h>
#include <hip/hip_fp16.h>
#include <math.h>

// VGAE Encoder on MI355X — R11.
// R10 refuted XCD-keyed atomic append: device-scope atomic grants serialize at
// fabric, interleaving slot owners across XCDs -> partial-line writebacks (51MB)
// no matter the slice key. R11 removes ALL global atomics from the CSR build:
//   k_chunksort : per-block LDS counting sort of a 4096-edge chunk by 256-node
//                 bucket; coalesced sorted-chunk write + (len<<13|base) SEG_T.
//   k_bucket256 : per-bucket block gathers its 391 chunk segments, LDS
//                 counting-sort by node -> rows2/xd/sorted_src (coalesced).
// k_mlp / k_agg2 unchanged from R9/R10 (f16 one-line-per-node table).

#define CH    4096     // edges per chunk
#define CAPB  4800     // per-bucket edge capacity (mean 4096, +11 sigma)

typedef float f32x4 __attribute__((ext_vector_type(4)));

__device__ __forceinline__ float2 cvt2(unsigned u) {
    __half2 h = *reinterpret_cast<__half2*>(&u);
    return __half22float2(h);
}

// Block-wide exclusive scan over arr[0..511] (pad unused with 0), 256 threads.
// arr becomes exclusive prefix; returns total of all 512. Internal barriers.
__device__ __forceinline__ int block_scan512(int* arr, int* tmp, int tid) {
    int v0 = arr[2 * tid], v1 = arr[2 * tid + 1];
    tmp[tid] = v0 + v1;
    __syncthreads();
    for (int off = 1; off < 256; off <<= 1) {
        int a = (tid >= off) ? tmp[tid - off] : 0;
        __syncthreads();
        tmp[tid] += a;
        __syncthreads();
    }
    int incl = tmp[tid];
    int base = incl - v0 - v1;
    arr[2 * tid] = base;
    arr[2 * tid + 1] = base + v0;
    int total = tmp[255];
    __syncthreads();
    return total;
}

// ---------- pass A: chunk-local counting sort by 256-node bucket ----------
__global__ void k_chunksort(const int* __restrict__ src, const int* __restrict__ dst,
                            unsigned* __restrict__ pairsc, unsigned* __restrict__ seg_t,
                            int E, int NC, int NBk) {
    __shared__ int hist[512];
    __shared__ int tmp[256];
    __shared__ int cur[392];
    __shared__ unsigned ebuf[CH];
    int c = blockIdx.x, tid = threadIdx.x;
    int e0 = c * CH;
    int n_e = min(CH, E - e0);

    hist[tid] = 0; hist[tid + 256] = 0;
    __syncthreads();
    for (int i = tid; i < n_e; i += 256) {
        int d = dst[e0 + i];
        atomicAdd(&hist[d >> 8], 1);
    }
    __syncthreads();
    int total = block_scan512(hist, tmp, tid);    // hist -> exclusive bases
    cur[tid] = hist[tid];
    if (tid < 136) cur[tid + 256] = hist[tid + 256];
    __syncthreads();
    for (int i = tid; i < n_e; i += 256) {
        int d = dst[e0 + i];
        int s = src[e0 + i];
        int slot = atomicAdd(&cur[d >> 8], 1);
        ebuf[slot] = ((unsigned)(d & 255) << 17) | (unsigned)s;   // s < 2^17
    }
    __syncthreads();
    for (int i = tid; i < n_e; i += 256)          // coalesced sorted-chunk write
        pairsc[(size_t)e0 + i] = ebuf[i];
    for (int b = tid; b < NBk; b += 256) {        // SEG_T[b][c] = len<<13 | base
        int base = hist[b];
        int next = (b + 1 < 512) ? hist[b + 1] : total;
        seg_t[(size_t)b * NC + c] = ((unsigned)(next - base) << 13) | (unsigned)base;
    }
}

// ---------- pass B: per-bucket concat + counting sort by node ----------
__global__ void k_bucket256(const unsigned* __restrict__ pairsc,
                            const unsigned* __restrict__ seg_t,
                            const float* __restrict__ x,
                            uint2* __restrict__ rows2, float2* __restrict__ xd,
                            int* __restrict__ sorted_src, int NC, int N) {
    __shared__ int coff[512];
    __shared__ int tmp[256];
    __shared__ int hist[512];
    __shared__ int cur[256];
    __shared__ unsigned segs[392];
    __shared__ unsigned lbuf[CAPB];
    __shared__ unsigned sbuf[CAPB];
    int b = blockIdx.x, tid = threadIdx.x;

    for (int c = tid; c < NC; c += 256) segs[c] = seg_t[(size_t)b * NC + c];
    coff[tid] = 0; coff[tid + 256] = 0;
    __syncthreads();
    for (int c = tid; c < NC; c += 256) coff[c] = (int)(segs[c] >> 13);
    __syncthreads();
    int tot = block_scan512(coff, tmp, tid);      // per-chunk dest offsets

    for (int c = tid; c < NC; c += 256) {         // gather segments -> lbuf
        unsigned sg = segs[c];
        int len = (int)(sg >> 13);
        int base = (int)(sg & 0x1FFFu);
        int doff = coff[c];
        const unsigned* p = pairsc + (size_t)c * CH + base;
        for (int j = 0; j < len; ++j) lbuf[doff + j] = p[j];
    }
    hist[tid] = 0; hist[tid + 256] = 0;
    __syncthreads();
    for (int i = tid; i < tot; i += 256) atomicAdd(&hist[lbuf[i] >> 17], 1);
    __syncthreads();
    int deg = hist[tid];                          // this thread's node degree
    block_scan512(hist, tmp, tid);
    int excl = hist[tid];
    int n = (b << 8) + tid;
    int ebase = b * CAPB;
    if (n < N) {
        float di = rsqrtf(1.0f + (float)deg);
        rows2[n] = make_uint2((unsigned)(ebase + excl) | ((unsigned)deg << 21),
                              __float_as_uint(di));
        float2 xv = ((const float2*)x)[n];
        xd[n] = make_float2(di * xv.x, di * xv.y);
    }
    cur[tid] = excl;
    __syncthreads();
    for (int i = tid; i < tot; i += 256) {        // sort by node in LDS
        unsigned pr = lbuf[i];
        int slot = atomicAdd(&cur[pr >> 17], 1);
        sbuf[slot] = pr & 0x1FFFFu;
    }
    __syncthreads();
    for (int i = tid; i < tot; i += 256)          // coalesced drain
        sorted_src[ebase + i] = (int)sbuf[i];
}

// ---------- fused gather + dense MLP: 32 lanes per node ----------
// ax = di*(xd[n] + sum_s xd[s]); h = relu(ax W1 + b1);
// hml' = f16( di * (h [W_mu|W_logstd]) ) — one 64B line per node.
__global__ void k_mlp(const float2* __restrict__ xd, const uint2* __restrict__ rows2,
                      const int* __restrict__ sorted_src,
                      const float* __restrict__ W1, const float* __restrict__ b1,
                      const float* __restrict__ W_mu, const float* __restrict__ W_logstd,
                      __half* __restrict__ hml16, int N) {
    __shared__ float W1s[128];
    __shared__ float b1s[64];
    __shared__ float Wcs[64 * 32];
    for (int t = threadIdx.x; t < 128; t += 256) W1s[t] = W1[t];
    for (int t = threadIdx.x; t < 64; t += 256) b1s[t] = b1[t];
    for (int t = threadIdx.x; t < 2048; t += 256) {
        int k = t >> 5, c = t & 31;
        Wcs[t] = (c < 16) ? W_mu[k * 16 + c] : W_logstd[k * 16 + (c - 16)];
    }
    __syncthreads();
    int node = blockIdx.x * 8 + (threadIdx.x >> 5);
    int c = threadIdx.x & 31;
    if (node >= N) return;
    uint2 r = rows2[node];
    int beg = (int)(r.x & 0x1FFFFFu);
    int end = beg + (int)(r.x >> 21);
    float di = __uint_as_float(r.y);
    float sx = 0.0f, sy = 0.0f;
    for (int e = beg + c; e < end; e += 32) {
        int s = sorted_src[e];
        float2 u = xd[s];
        sx += u.x;
        sy += u.y;
    }
#pragma unroll
    for (int off = 16; off; off >>= 1) {
        sx += __shfl_xor(sx, off, 32);
        sy += __shfl_xor(sy, off, 32);
    }
    float2 xn = xd[node];
    float axx = di * (sx + xn.x);
    float axy = di * (sy + xn.y);
    float h0 = fmaxf(fmaf(axx, W1s[c],      fmaf(axy, W1s[64 + c],  b1s[c])),      0.0f);
    float h1 = fmaxf(fmaf(axx, W1s[32 + c], fmaf(axy, W1s[96 + c],  b1s[32 + c])), 0.0f);
    float acc = 0.0f;
#pragma unroll
    for (int k = 0; k < 32; ++k) {
        float hk = __shfl(h0, k, 32);
        acc = fmaf(hk, Wcs[k * 32 + c], acc);
    }
#pragma unroll
    for (int k = 0; k < 32; ++k) {
        float hk = __shfl(h1, k, 32);
        acc = fmaf(hk, Wcs[(k + 32) * 32 + c], acc);
    }
    hml16[(size_t)node * 32 + c] = __float2half(di * acc);   // hml' = dis * hml
}

// ---------- layer-2 aggregation: single pass, 4 lanes/node, f16 table ----------
// out[n] = di * (hml'[n] + sum_s hml'[s]) + bias
__global__ void k_agg2(const __half* __restrict__ hml16, const uint2* __restrict__ rows2,
                       const int* __restrict__ sorted_src,
                       const float* __restrict__ b_mu, const float* __restrict__ b_logstd,
                       float* __restrict__ out, int N) {
    int t = blockIdx.x * blockDim.x + threadIdx.x;
    int node = t >> 2, q = t & 3;                   // lane q: channels 8q..8q+7
    if (node >= N) return;
    const uint4* h4 = (const uint4*)hml16;          // 16B = 8 f16 channels
    uint2 r = rows2[node];
    int beg = (int)(r.x & 0x1FFFFFu);
    int end = beg + (int)(r.x >> 21);
    float di = __uint_as_float(r.y);
    uint4 v = h4[(size_t)node * 4 + q];             // self-loop row
    float2 a0 = cvt2(v.x), a1 = cvt2(v.y), a2 = cvt2(v.z), a3 = cvt2(v.w);
    for (int k = beg; k < end; ++k) {
        int s = sorted_src[k];
        uint4 u = h4[(size_t)s * 4 + q];
        float2 t0 = cvt2(u.x), t1 = cvt2(u.y), t2 = cvt2(u.z), t3 = cvt2(u.w);
        a0.x += t0.x; a0.y += t0.y; a1.x += t1.x; a1.y += t1.y;
        a2.x += t2.x; a2.y += t2.y; a3.x += t3.x; a3.y += t3.y;
    }
    const float* bp = (q < 2) ? (b_mu + 8 * q) : (b_logstd + 8 * (q - 2));
    float* op = out + ((q < 2) ? (size_t)0 : (size_t)N * 16)
                    + (size_t)node * 16 + (size_t)(q & 1) * 8;
    f32x4 r0 = { fmaf(di, a0.x, bp[0]), fmaf(di, a0.y, bp[1]),
                 fmaf(di, a1.x, bp[2]), fmaf(di, a1.y, bp[3]) };
    f32x4 r1 = { fmaf(di, a2.x, bp[4]), fmaf(di, a2.y, bp[5]),
                 fmaf(di, a3.x, bp[6]), fmaf(di, a3.y, bp[7]) };
    *(f32x4*)op = r0;
    *(f32x4*)(op + 4) = r1;
}

extern "C" void kernel_launch(void* const* d_in, const int* in_sizes, int n_in,
                              void* d_out, int out_size, void* d_ws, size_t ws_size,
                              hipStream_t stream) {
    const float* x        = (const float*)d_in[0];
    const int*   eidx     = (const int*)d_in[1];
    const float* W1       = (const float*)d_in[2];
    const float* b1       = (const float*)d_in[3];
    const float* W_mu     = (const float*)d_in[4];
    const float* b_mu     = (const float*)d_in[5];
    const float* W_logstd = (const float*)d_in[6];
    const float* b_logstd = (const float*)d_in[7];
    float* out = (float*)d_out;

    const int N = in_sizes[0] / 2;            // 100000
    const int E = in_sizes[1] / 2;            // 1600000
    const int NC  = (E + CH - 1) / CH;        // 391 chunks
    const int NBk = (N + 255) >> 8;           // 391 buckets of 256 nodes

    const int* src = eidx;
    const int* dst = eidx + E;

    char* w = (char*)d_ws;
    auto alloc = [&](size_t bytes) -> void* {
        void* p = (void*)w;
        w += (bytes + 255) & ~(size_t)255;
        return p;
    };
    unsigned* pairsc     = (unsigned*)alloc((size_t)NC * CH * 4);
    unsigned* seg_t      = (unsigned*)alloc((size_t)NBk * NC * 4);
    int*      sorted_src = (int*)     alloc((size_t)NBk * CAPB * 4);
    uint2*    rows2      = (uint2*)   alloc((size_t)N * 8);
    float2*   xd         = (float2*)  alloc((size_t)N * 8);
    __half*   hml16      = (__half*)  alloc((size_t)N * 32 * 2);

    k_chunksort<<<NC, 256, 0, stream>>>(src, dst, pairsc, seg_t, E, NC, NBk);
    k_bucket256<<<NBk, 256, 0, stream>>>(pairsc, seg_t, x, rows2, xd,
                                         sorted_src, NC, N);
    k_mlp      <<<(N + 7) / 8, 256, 0, stream>>>(xd, rows2, sorted_src,
                                                 W1, b1, W_mu, W_logstd, hml16, N);
    k_agg2     <<<(4 * N + 255) / 256, 256, 0, stream>>>(hml16, rows2, sorted_src,
                                                         b_mu, b_logstd, out, N);
}

// Round 12
// 171.196 us; speedup vs baseline: 2.0198x; 1.1125x over previous
//
#include <hip/hip_runtime.h>
#include <hip/hip_fp16.h>
#include <math.h>

// VGAE Encoder on MI355X — R12.
// R11: k_mlp 62us at 2.9% HBM / 26% VALU — latency-bound: 2 nodes/wave, 128-deep
// serial FMA chain, 128 DS ops per wave. R12 k_mlp: 16 lanes/node (4 nodes/wave),
// channel-paired float2 (mu,logstd) so Wc reads are one ds_read_b64 w/ imm offset,
// W1 slice in registers (no DS for h), 4 independent accumulator chains.
// hml16 stored interleaved (mu,ls) half2; agg2 deinterleaves on store.
// chunksort/bucket256 (atomic-free CSR, R11) unchanged.

#define CH    4096     // edges per chunk
#define CAPB  4800     // per-bucket edge capacity (mean 4096, +11 sigma)

typedef float f32x4 __attribute__((ext_vector_type(4)));

__device__ __forceinline__ float2 cvt2(unsigned u) {
    __half2 h = *reinterpret_cast<__half2*>(&u);
    return __half22float2(h);
}

// Block-wide exclusive scan over arr[0..511] (pad unused with 0), 256 threads.
__device__ __forceinline__ int block_scan512(int* arr, int* tmp, int tid) {
    int v0 = arr[2 * tid], v1 = arr[2 * tid + 1];
    tmp[tid] = v0 + v1;
    __syncthreads();
    for (int off = 1; off < 256; off <<= 1) {
        int a = (tid >= off) ? tmp[tid - off] : 0;
        __syncthreads();
        tmp[tid] += a;
        __syncthreads();
    }
    int incl = tmp[tid];
    int base = incl - v0 - v1;
    arr[2 * tid] = base;
    arr[2 * tid + 1] = base + v0;
    int total = tmp[255];
    __syncthreads();
    return total;
}

// ---------- pass A: chunk-local counting sort by 256-node bucket ----------
__global__ void k_chunksort(const int* __restrict__ src, const int* __restrict__ dst,
                            unsigned* __restrict__ pairsc, unsigned* __restrict__ seg_t,
                            int E, int NC, int NBk) {
    __shared__ int hist[512];
    __shared__ int tmp[256];
    __shared__ int cur[392];
    __shared__ unsigned ebuf[CH];
    int c = blockIdx.x, tid = threadIdx.x;
    int e0 = c * CH;
    int n_e = min(CH, E - e0);

    hist[tid] = 0; hist[tid + 256] = 0;
    __syncthreads();
    for (int i = tid; i < n_e; i += 256) {
        int d = dst[e0 + i];
        atomicAdd(&hist[d >> 8], 1);
    }
    __syncthreads();
    int total = block_scan512(hist, tmp, tid);    // hist -> exclusive bases
    cur[tid] = hist[tid];
    if (tid < 136) cur[tid + 256] = hist[tid + 256];
    __syncthreads();
    for (int i = tid; i < n_e; i += 256) {
        int d = dst[e0 + i];
        int s = src[e0 + i];
        int slot = atomicAdd(&cur[d >> 8], 1);
        ebuf[slot] = ((unsigned)(d & 255) << 17) | (unsigned)s;   // s < 2^17
    }
    __syncthreads();
    for (int i = tid; i < n_e; i += 256)          // coalesced sorted-chunk write
        pairsc[(size_t)e0 + i] = ebuf[i];
    for (int b = tid; b < NBk; b += 256) {        // SEG_T[b][c] = len<<13 | base
        int base = hist[b];
        int next = (b + 1 < 512) ? hist[b + 1] : total;
        seg_t[(size_t)b * NC + c] = ((unsigned)(next - base) << 13) | (unsigned)base;
    }
}

// ---------- pass B: per-bucket concat + counting sort by node ----------
__global__ void k_bucket256(const unsigned* __restrict__ pairsc,
                            const unsigned* __restrict__ seg_t,
                            const float* __restrict__ x,
                            uint2* __restrict__ rows2, float2* __restrict__ xd,
                            int* __restrict__ sorted_src, int NC, int N) {
    __shared__ int coff[512];
    __shared__ int tmp[256];
    __shared__ int hist[512];
    __shared__ int cur[256];
    __shared__ unsigned segs[392];
    __shared__ unsigned lbuf[CAPB];
    __shared__ unsigned sbuf[CAPB];
    int b = blockIdx.x, tid = threadIdx.x;

    for (int c = tid; c < NC; c += 256) segs[c] = seg_t[(size_t)b * NC + c];
    coff[tid] = 0; coff[tid + 256] = 0;
    __syncthreads();
    for (int c = tid; c < NC; c += 256) coff[c] = (int)(segs[c] >> 13);
    __syncthreads();
    int tot = block_scan512(coff, tmp, tid);      // per-chunk dest offsets

    for (int c = tid; c < NC; c += 256) {         // gather segments -> lbuf
        unsigned sg = segs[c];
        int len = (int)(sg >> 13);
        int base = (int)(sg & 0x1FFFu);
        int doff = coff[c];
        const unsigned* p = pairsc + (size_t)c * CH + base;
        for (int j = 0; j < len; ++j) lbuf[doff + j] = p[j];
    }
    hist[tid] = 0; hist[tid + 256] = 0;
    __syncthreads();
    for (int i = tid; i < tot; i += 256) atomicAdd(&hist[lbuf[i] >> 17], 1);
    __syncthreads();
    int deg = hist[tid];                          // this thread's node degree
    block_scan512(hist, tmp, tid);
    int excl = hist[tid];
    int n = (b << 8) + tid;
    int ebase = b * CAPB;
    if (n < N) {
        float di = rsqrtf(1.0f + (float)deg);
        rows2[n] = make_uint2((unsigned)(ebase + excl) | ((unsigned)deg << 21),
                              __float_as_uint(di));
        float2 xv = ((const float2*)x)[n];
        xd[n] = make_float2(di * xv.x, di * xv.y);
    }
    cur[tid] = excl;
    __syncthreads();
    for (int i = tid; i < tot; i += 256) {        // sort by node in LDS
        unsigned pr = lbuf[i];
        int slot = atomicAdd(&cur[pr >> 17], 1);
        sbuf[slot] = pr & 0x1FFFFu;
    }
    __syncthreads();
    for (int i = tid; i < tot; i += 256)          // coalesced drain
        sorted_src[ebase + i] = (int)sbuf[i];
}

// ---------- fused gather + dense MLP: 16 lanes per node, 4 nodes/wave ----------
// ax = di*(xd[n] + sum_s xd[s]); h = relu(ax W1 + b1);
// lane c2 owns channels (c2, c2+16): hml'2[node][c2] = half2{mu_c2, ls_c2} * di
__global__ void k_mlp(const float2* __restrict__ xd, const uint2* __restrict__ rows2,
                      const int* __restrict__ sorted_src,
                      const float* __restrict__ W1, const float* __restrict__ b1,
                      const float* __restrict__ W_mu, const float* __restrict__ W_logstd,
                      __half2* __restrict__ hml16, int N) {
    __shared__ float2 Wp[64 * 16];                // Wp[k][c2] = {Wmu[k][c2], Wls[k][c2]}
    int tid = threadIdx.x;
    for (int t = tid; t < 1024; t += 256) {
        int k = t >> 4, c2 = t & 15;
        Wp[t] = make_float2(W_mu[k * 16 + c2], W_logstd[k * 16 + c2]);
    }
    int c2 = tid & 15;
    // W1 slice in registers: k_j = c2 + 16j
    float w1a[4], w1b[4], bb[4];
#pragma unroll
    for (int j = 0; j < 4; ++j) {
        w1a[j] = W1[c2 + 16 * j];
        w1b[j] = W1[64 + c2 + 16 * j];
        bb[j]  = b1[c2 + 16 * j];
    }
    __syncthreads();
    int node = blockIdx.x * 16 + (tid >> 4);
    if (node >= N) return;
    uint2 r = rows2[node];
    int beg = (int)(r.x & 0x1FFFFFu);
    int end = beg + (int)(r.x >> 21);
    float di = __uint_as_float(r.y);
    float sx = 0.0f, sy = 0.0f;
    for (int e = beg + c2; e < end; e += 16) {
        int s = sorted_src[e];
        float2 u = xd[s];
        sx += u.x;
        sy += u.y;
    }
#pragma unroll
    for (int off = 8; off; off >>= 1) {
        sx += __shfl_xor(sx, off, 16);
        sy += __shfl_xor(sy, off, 16);
    }
    float2 xn = xd[node];
    float axx = di * (sx + xn.x);
    float axy = di * (sy + xn.y);
    float h[4];
#pragma unroll
    for (int j = 0; j < 4; ++j)
        h[j] = fmaxf(fmaf(axx, w1a[j], fmaf(axy, w1b[j], bb[j])), 0.0f);
    // 4 independent accumulator chains (one per k-quartile)
    float2 a0 = make_float2(0.f, 0.f), a1 = a0, a2 = a0, a3 = a0;
#pragma unroll
    for (int kk = 0; kk < 16; ++kk) {
        float h0 = __shfl(h[0], kk, 16);
        float h1 = __shfl(h[1], kk, 16);
        float h2 = __shfl(h[2], kk, 16);
        float h3 = __shfl(h[3], kk, 16);
        float2 w0 = Wp[kk * 16 + c2];
        float2 w1 = Wp[(16 + kk) * 16 + c2];
        float2 w2 = Wp[(32 + kk) * 16 + c2];
        float2 w3 = Wp[(48 + kk) * 16 + c2];
        a0.x = fmaf(h0, w0.x, a0.x); a0.y = fmaf(h0, w0.y, a0.y);
        a1.x = fmaf(h1, w1.x, a1.x); a1.y = fmaf(h1, w1.y, a1.y);
        a2.x = fmaf(h2, w2.x, a2.x); a2.y = fmaf(h2, w2.y, a2.y);
        a3.x = fmaf(h3, w3.x, a3.x); a3.y = fmaf(h3, w3.y, a3.y);
    }
    float mu = di * ((a0.x + a1.x) + (a2.x + a3.x));
    float ls = di * ((a0.y + a1.y) + (a2.y + a3.y));
    hml16[(size_t)node * 16 + c2] = __floats2half2_rn(mu, ls);
}

// ---------- layer-2 aggregation: single pass, 4 lanes/node, f16 table ----------
// table row = 16 x half2{mu,ls}; lane q owns channel pairs 4q..4q+3.
// out[n] = di * (row[n] + sum_s row[s]) + bias, deinterleaved on store.
__global__ void k_agg2(const __half2* __restrict__ hml16, const uint2* __restrict__ rows2,
                       const int* __restrict__ sorted_src,
                       const float* __restrict__ b_mu, const float* __restrict__ b_logstd,
                       float* __restrict__ out, int N) {
    int t = blockIdx.x * blockDim.x + threadIdx.x;
    int node = t >> 2, q = t & 3;
    if (node >= N) return;
    const uint4* h4 = (const uint4*)hml16;          // 16B = 4 half2 pairs
    uint2 r = rows2[node];
    int beg = (int)(r.x & 0x1FFFFFu);
    int end = beg + (int)(r.x >> 21);
    float di = __uint_as_float(r.y);
    uint4 v = h4[(size_t)node * 4 + q];             // self-loop row
    float2 a0 = cvt2(v.x), a1 = cvt2(v.y), a2 = cvt2(v.z), a3 = cvt2(v.w);
    for (int k = beg; k < end; ++k) {
        int s = sorted_src[k];
        uint4 u = h4[(size_t)s * 4 + q];
        float2 t0 = cvt2(u.x), t1 = cvt2(u.y), t2 = cvt2(u.z), t3 = cvt2(u.w);
        a0.x += t0.x; a0.y += t0.y; a1.x += t1.x; a1.y += t1.y;
        a2.x += t2.x; a2.y += t2.y; a3.x += t3.x; a3.y += t3.y;
    }
    float4 bm = *(const float4*)(b_mu + 4 * q);
    float4 bl = *(const float4*)(b_logstd + 4 * q);
    f32x4 mu = { fmaf(di, a0.x, bm.x), fmaf(di, a1.x, bm.y),
                 fmaf(di, a2.x, bm.z), fmaf(di, a3.x, bm.w) };
    f32x4 ls = { fmaf(di, a0.y, bl.x), fmaf(di, a1.y, bl.y),
                 fmaf(di, a2.y, bl.z), fmaf(di, a3.y, bl.w) };
    *(f32x4*)(out + (size_t)node * 16 + 4 * q) = mu;
    *(f32x4*)(out + (size_t)(N + node) * 16 + 4 * q) = ls;
}

extern "C" void kernel_launch(void* const* d_in, const int* in_sizes, int n_in,
                              void* d_out, int out_size, void* d_ws, size_t ws_size,
                              hipStream_t stream) {
    const float* x        = (const float*)d_in[0];
    const int*   eidx     = (const int*)d_in[1];
    const float* W1       = (const float*)d_in[2];
    const float* b1       = (const float*)d_in[3];
    const float* W_mu     = (const float*)d_in[4];
    const float* b_mu     = (const float*)d_in[5];
    const float* W_logstd = (const float*)d_in[6];
    const float* b_logstd = (const float*)d_in[7];
    float* out = (float*)d_out;

    const int N = in_sizes[0] / 2;            // 100000
    const int E = in_sizes[1] / 2;            // 1600000
    const int NC  = (E + CH - 1) / CH;        // 391 chunks
    const int NBk = (N + 255) >> 8;           // 391 buckets of 256 nodes

    const int* src = eidx;
    const int* dst = eidx + E;

    char* w = (char*)d_ws;
    auto alloc = [&](size_t bytes) -> void* {
        void* p = (void*)w;
        w += (bytes + 255) & ~(size_t)255;
        return p;
    };
    unsigned* pairsc     = (unsigned*)alloc((size_t)NC * CH * 4);
    unsigned* seg_t      = (unsigned*)alloc((size_t)NBk * NC * 4);
    int*      sorted_src = (int*)     alloc((size_t)NBk * CAPB * 4);
    uint2*    rows2      = (uint2*)   alloc((size_t)N * 8);
    float2*   xd         = (float2*)  alloc((size_t)N * 8);
    __half2*  hml16      = (__half2*) alloc((size_t)N * 16 * 4);

    k_chunksort<<<NC, 256, 0, stream>>>(src, dst, pairsc, seg_t, E, NC, NBk);
    k_bucket256<<<NBk, 256, 0, stream>>>(pairsc, seg_t, x, rows2, xd,
                                         sorted_src, NC, N);
    k_mlp      <<<(N + 15) / 16, 256, 0, stream>>>(xd, rows2, sorted_src,
                                                   W1, b1, W_mu, W_logstd, hml16, N);
    k_agg2     <<<(4 * N + 255) / 256, 256, 0, stream>>>(hml16, rows2, sorted_src,
                                                         b_mu, b_logstd, out, N);
}